// Round 1
// 2378.879 us; speedup vs baseline: 1.1361x; 1.1361x over previous
//
#include <hip/hip_runtime.h>
#include <stdint.h>
#include <stddef.h>

#define NB 1024
#define TB 1024
#define D_IN 6
#define UNITS 64
#define WIDTH 128
#define DOUT 6
#define EPSF 1e-8f
#define SPB 16          // samples per block (one 16-row MFMA tile)
#define LDK0 108        // c0 row stride (halfs): conflict-free (54 dw == 22 mod 32)
#define LDK 140         // cP/cQ/cG row stride (halfs): conflict-free (70 dw == 6 mod 32)

typedef _Float16 v8h __attribute__((ext_vector_type(8)));
typedef float v4f __attribute__((ext_vector_type(4)));

#define MFMAH(A,Bf,C) __builtin_amdgcn_mfma_f32_16x16x32_f16((A),(Bf),(C),0,0,0)

// LDS-only barrier: orders LDS across the block, does NOT drain vmcnt.
#define BARRIER_LDS() asm volatile("s_waitcnt lgkmcnt(0)\n\ts_barrier" ::: "memory")

#define C2L2E  2.8853900817779268f    // 2*log2(e)
#define L2E    1.4426950408889634f    // log2(e)
#define NEGL2E (-1.4426950408889634f)

__device__ __forceinline__ float rcp_fast(float x){ return __builtin_amdgcn_rcpf(x); }

// tanh via exp2 on the transcendental pipe: tanh(y) = 1 - 2/(1 + 2^(y*2log2e)).
// Caller passes a2 = y*C2L2E (bias can be pre-folded into the fma forming a2).
// 5 instrs (fma/mul, v_exp, add, v_rcp, fma); saturates correctly for |y| large;
// err ~1e-7 (better than the Pade it replaces).
__device__ __forceinline__ float tanh_from_arg(float a2){
  float u = __builtin_amdgcn_exp2f(a2);
  return fmaf(-2.0f, rcp_fast(u + 1.0f), 1.0f);
}
__device__ __forceinline__ float tanh_e(float x){ return tanh_from_arg(x * C2L2E); }

__device__ __forceinline__ void make_frag1(const float* vals, v8h& hv){
  #pragma unroll
  for (int j = 0; j < 8; j++) hv[j] = (_Float16)vals[j];
}
__device__ __forceinline__ void make_frag2(const float* vals, v8h& hv, v8h& lv){
  #pragma unroll
  for (int j = 0; j < 8; j++){
    _Float16 h = (_Float16)vals[j];
    hv[j] = h;
    lv[j] = (_Float16)(vals[j] - (float)h);
  }
}

__global__ __launch_bounds__(512, 2) void lmsc_kernel(
    const float* __restrict__ x, const float* __restrict__ initF,
    const float* __restrict__ w10, const float* __restrict__ b10,
    const float* __restrict__ w20, const float* __restrict__ b20,
    const float* __restrict__ w11, const float* __restrict__ b11,
    const float* __restrict__ w21, const float* __restrict__ b21,
    const float* __restrict__ w12, const float* __restrict__ b12,
    const float* __restrict__ w22, const float* __restrict__ b22,
    const float* __restrict__ wa, const float* __restrict__ ba,
    const float* __restrict__ wb, const float* __restrict__ bb,
    const float* __restrict__ wo,
    float* __restrict__ outs, float* __restrict__ alph)
{
  // ---- LDS: ~20 KB ----
  __shared__ __attribute__((aligned(16))) _Float16 c0[2][SPB*LDK0];  // t-parity double buffer
  __shared__ __attribute__((aligned(16))) _Float16 cP[SPB*LDK];
  __shared__ __attribute__((aligned(16))) _Float16 cQ[SPB*LDK];
  __shared__ __attribute__((aligned(16))) _Float16 cG[SPB*LDK];
  __shared__ __attribute__((aligned(16))) float nrm[2][SPB];         // stores -log2e * ||x||

  const int tid = threadIdx.x;
  const int wv = tid >> 6;       // wave 0..7
  const int ln = tid & 63;
  const int mn = ln & 15;
  const int qd = ln >> 4;
  const int q8 = qd * 8;
  const int n  = wv * 16 + mn;   // col for WIDTH=128 layers (wave owns 16 cols)
  const int sgbase = (int)blockIdx.x * SPB;

  float tmp[8];

  // ---------------- one-time weight fragments (registers) ----------------
  // L0: single fp16; K through c0 cols (xn 0..5, h 8..71), 3 kf
  v8h B0[3][2];
  #pragma unroll
  for (int kf = 0; kf < 3; kf++)
    #pragma unroll
    for (int br = 0; br < 2; br++){
      const float* W = br ? w20 : w10;
      #pragma unroll
      for (int j = 0; j < 8; j++){
        int k = kf*32 + q8 + j;
        int r = (k < 6) ? k : ((k >= 8 && k < 72) ? (k - 2) : -1);
        tmp[j] = (r >= 0) ? W[r*WIDTH + n] : 0.0f;
      }
      make_frag1(tmp, B0[kf][br]);
    }

  // L1, L2: single fp16
  v8h B1[4][2], B2[4][2];
  #pragma unroll
  for (int kf = 0; kf < 4; kf++)
    #pragma unroll
    for (int br = 0; br < 2; br++){
      const float* W = br ? w21 : w11;
      #pragma unroll
      for (int j = 0; j < 8; j++)
        tmp[j] = W[(kf*32 + q8 + j)*WIDTH + n];
      make_frag1(tmp, B1[kf][br]);
      const float* V = br ? w22 : w12;
      #pragma unroll
      for (int j = 0; j < 8; j++)
        tmp[j] = V[(kf*32 + q8 + j)*WIDTH + n];
      make_frag1(tmp, B2[kf][br]);
    }

  // D-phase: wave (wv&3) owns units u..u+15; wa hi+lo (alpha path), wb single (beta)
  const int u = (wv & 3) * 16 + mn;
  v8h Bah[4], Bal[4], Bbh[4];
  #pragma unroll
  for (int kf = 0; kf < 4; kf++){
    #pragma unroll
    for (int j = 0; j < 8; j++)
      tmp[j] = wa[(kf*32 + q8 + j)*UNITS + u];
    make_frag2(tmp, Bah[kf], Bal[kf]);
    #pragma unroll
    for (int j = 0; j < 8; j++)
      tmp[j] = wb[(kf*32 + q8 + j)*UNITS + u];
    make_frag1(tmp, Bbh[kf]);
  }
  const float bsa = ba[u];
  const float bsb = bb[u];

  // wout (K=64 over h, N=6 padded to 16): single fp16 (used by wave 7)
  v8h Woh0, Woh1;
  #pragma unroll
  for (int j = 0; j < 8; j++)
    tmp[j] = (mn < DOUT) ? wo[(q8 + j)*DOUT + mn] : 0.0f;
  make_frag1(tmp, Woh0);
  #pragma unroll
  for (int j = 0; j < 8; j++)
    tmp[j] = (mn < DOUT) ? wo[(32 + q8 + j)*DOUT + mn] : 0.0f;
  make_frag1(tmp, Woh1);

  const float bs0a = b10[n], bs0b = b20[n];
  const float bs1a = b11[n], bs1b = b21[n];
  const float bs2a = b12[n], bs2b = b22[n];
  // biases of L0/L1 pre-scaled for direct fold into the exp2 argument
  const float e0a = bs0a * C2L2E, e0b = bs0b * C2L2E;
  const float e1a = bs1a * C2L2E, e1b = bs1b * C2L2E;

  // hoisted global-store bases (loop-invariant 64-bit address math)
  float* alp  = alph + ((size_t)(sgbase + qd*4) * TB) * UNITS + u;          // waves 0-3 (bumped +UNITS/step)
  float* outp = outs + ((size_t)(sgbase + qd*4) * TB) * DOUT + mn;          // wave 7

  // ---------------- init ----------------
  for (int i = tid; i < 2*SPB*LDK0; i += 512) c0[0][i] = (_Float16)0.0f;
  __syncthreads();

  // h persistent in registers of waves 0-3 (C-layout: col=unit=u, row=sample=qd*4+r)
  float hreg[4];
  if (wv < 4){
    #pragma unroll
    for (int r = 0; r < 4; r++){
      int s = qd*4 + r;
      float v = initF[(size_t)(sgbase + s)*(2 + UNITS) + 2 + u];
      hreg[r] = v;
      c0[0][s*LDK0 + 8 + u] = (_Float16)v;
    }
  }
  float xv0=0, xv1=0, xv2=0, xv3=0, xv4=0, xv5=0;
  if (wv == 4 && ln < 16){
    const float* xp = x + (size_t)(sgbase + ln)*TB*D_IN;
    float a0=xp[0], a1=xp[1], a2=xp[2], a3=xp[3], a4=xp[4], a5=xp[5];
    float nv = sqrtf(a0*a0 + a1*a1 + a2*a2 + a3*a3 + a4*a4 + a5*a5);
    nrm[0][ln] = nv * NEGL2E;
    float inv = 1.0f / (nv + EPSF);
    c0[0][ln*LDK0 + 0] = (_Float16)(a0*inv);
    c0[0][ln*LDK0 + 1] = (_Float16)(a1*inv);
    c0[0][ln*LDK0 + 2] = (_Float16)(a2*inv);
    c0[0][ln*LDK0 + 3] = (_Float16)(a3*inv);
    c0[0][ln*LDK0 + 4] = (_Float16)(a4*inv);
    c0[0][ln*LDK0 + 5] = (_Float16)(a5*inv);
    xv0 = xp[6]; xv1 = xp[7]; xv2 = xp[8]; xv3 = xp[9]; xv4 = xp[10]; xv5 = xp[11];  // x(t=1)
  }
  __syncthreads();

  auto wout_phase = [&](const _Float16* cb, int tt){
    v8h ah0 = *(const v8h*)(cb + mn*LDK0 + 8 + q8);
    v8h ah1 = *(const v8h*)(cb + mn*LDK0 + 40 + q8);
    v4f acc = {0.f, 0.f, 0.f, 0.f};
    acc = MFMAH(ah0, Woh0, acc);
    acc = MFMAH(ah1, Woh1, acc);
    if (mn < DOUT){
      #pragma unroll
      for (int r = 0; r < 4; r++)
        outp[(size_t)r*TB*DOUT + (size_t)tt*DOUT] = acc[r];
    }
  };

  // ================= time loop (4 LDS-only barriers/step) =================
  for (int t = 0; t < TB; t++){
    const int p = t & 1;
    const _Float16* c0r = c0[p];
    _Float16* c0w = c0[p ^ 1];

    // ---- Phase A: L0 (c0[p] -> cP), biases folded into exp2 arg ----
    {
      v8h ah[3];
      #pragma unroll
      for (int kf = 0; kf < 3; kf++)
        ah[kf] = *(const v8h*)(c0r + mn*LDK0 + kf*32 + q8);
      v4f acc0 = {0.f, 0.f, 0.f, 0.f};
      v4f acc1 = {0.f, 0.f, 0.f, 0.f};
      #pragma unroll
      for (int kf = 0; kf < 3; kf++){
        acc0 = MFMAH(ah[kf], B0[kf][0], acc0);
        acc1 = MFMAH(ah[kf], B0[kf][1], acc1);
      }
      #pragma unroll
      for (int r = 0; r < 4; r++){
        float t0 = tanh_from_arg(fmaf(acc0[r], C2L2E, e0a));
        float t1 = tanh_from_arg(fmaf(acc1[r], C2L2E, e0b));
        cP[(qd*4 + r)*LDK + n] = (_Float16)(t0 * t1);
      }
    }
    BARRIER_LDS();  // b1

    // ---- Phase B: L1 (cP -> cQ) ----
    {
      v8h ah[4];
      #pragma unroll
      for (int kf = 0; kf < 4; kf++)
        ah[kf] = *(const v8h*)(cP + mn*LDK + kf*32 + q8);
      v4f acc0 = {0.f, 0.f, 0.f, 0.f};
      v4f acc1 = {0.f, 0.f, 0.f, 0.f};
      #pragma unroll
      for (int kf = 0; kf < 4; kf++){
        acc0 = MFMAH(ah[kf], B1[kf][0], acc0);
        acc1 = MFMAH(ah[kf], B1[kf][1], acc1);
      }
      #pragma unroll
      for (int r = 0; r < 4; r++){
        float t0 = tanh_from_arg(fmaf(acc0[r], C2L2E, e1a));
        float t1 = tanh_from_arg(fmaf(acc1[r], C2L2E, e1b));
        cQ[(qd*4 + r)*LDK + n] = (_Float16)(t0 * t1);
      }
    }
    BARRIER_LDS();  // b2

    // ---- Phase C: L2 (cQ -> g), g = tanh(x1*x2) (biases in acc init) ----
    {
      v8h ah[4];
      #pragma unroll
      for (int kf = 0; kf < 4; kf++)
        ah[kf] = *(const v8h*)(cQ + mn*LDK + kf*32 + q8);
      v4f acc0 = {bs2a, bs2a, bs2a, bs2a};
      v4f acc1 = {bs2b, bs2b, bs2b, bs2b};
      #pragma unroll
      for (int kf = 0; kf < 4; kf++){
        acc0 = MFMAH(ah[kf], B2[kf][0], acc0);
        acc1 = MFMAH(ah[kf], B2[kf][1], acc1);
      }
      #pragma unroll
      for (int r = 0; r < 4; r++)
        cG[(qd*4 + r)*LDK + n] = (_Float16)tanh_e(acc0[r] * acc1[r]);
    }
    BARRIER_LDS();  // b3

    // ---- Phase D:
    //   waves 0-3: pA (wa hi+lo) + pB for 16 units; h-update in regs;
    //              h(t) -> c0[p^1], alpha -> global (un-drained store)
    //   wave 7:    wout(t-1) from c0[p]
    //   wave 4:    x-norm(t+1) -> c0[p^1], prefetch x(t+2)
    if (wv < 4){
      v8h gh[4];
      #pragma unroll
      for (int kf = 0; kf < 4; kf++)
        gh[kf] = *(const v8h*)(cG + mn*LDK + kf*32 + q8);
      v4f pA0 = {bsa, bsa, bsa, bsa};
      v4f pA1 = {0.f, 0.f, 0.f, 0.f};
      v4f pB  = {bsb, bsb, bsb, bsb};
      #pragma unroll
      for (int kf = 0; kf < 2; kf++){
        pA0 = MFMAH(gh[kf], Bah[kf], pA0);
        pA0 = MFMAH(gh[kf], Bal[kf], pA0);
        pA1 = MFMAH(gh[kf+2], Bah[kf+2], pA1);
        pA1 = MFMAH(gh[kf+2], Bal[kf+2], pA1);
        pB  = MFMAH(gh[2*kf],   Bbh[2*kf],   pB);
        pB  = MFMAH(gh[2*kf+1], Bbh[2*kf+1], pB);
      }
      #pragma unroll
      for (int r = 0; r < 4; r++){
        int s = qd*4 + r;
        float m = nrm[p][s];                                   // -log2e * norm
        float alpha = __builtin_amdgcn_exp2f((pA0[r] + pA1[r]) * L2E);
        float beta  = tanh_e(pB[r]);
        float dec   = __builtin_amdgcn_exp2f(alpha * m);       // exp(-alpha*norm)
        float h = fmaf(dec, hreg[r] - beta, beta);
        hreg[r] = h;
        c0w[s*LDK0 + 8 + u] = (_Float16)h;
        alp[(size_t)r*TB*UNITS] = alpha;
      }
      alp += UNITS;
    } else if (wv == 7){
      if (t > 0) wout_phase(c0r, t - 1);
    } else if (wv == 4 && ln < 16){
      float nv2 = sqrtf(xv0*xv0 + xv1*xv1 + xv2*xv2 + xv3*xv3 + xv4*xv4 + xv5*xv5);
      nrm[p ^ 1][ln] = nv2 * NEGL2E;
      float inv = 1.0f / (nv2 + EPSF);
      c0w[ln*LDK0 + 0] = (_Float16)(xv0*inv);
      c0w[ln*LDK0 + 1] = (_Float16)(xv1*inv);
      c0w[ln*LDK0 + 2] = (_Float16)(xv2*inv);
      c0w[ln*LDK0 + 3] = (_Float16)(xv3*inv);
      c0w[ln*LDK0 + 4] = (_Float16)(xv4*inv);
      c0w[ln*LDK0 + 5] = (_Float16)(xv5*inv);
      int tn = t + 2; if (tn > TB - 1) tn = TB - 1;
      const float* xp = x + ((size_t)(sgbase + ln)*TB + (size_t)tn)*D_IN;
      xv0 = xp[0]; xv1 = xp[1]; xv2 = xp[2]; xv3 = xp[3]; xv4 = xp[4]; xv5 = xp[5];
    }
    BARRIER_LDS();  // b4
  }

  // final wout(TB-1): h(TB-1) sits in c0[0]
  if (wv == 7) wout_phase(c0[TB & 1], TB - 1);
}

extern "C" void kernel_launch(void* const* d_in, const int* in_sizes, int n_in,
                              void* d_out, int out_size, void* d_ws, size_t ws_size,
                              hipStream_t stream) {
  const float* x    = (const float*)d_in[0];
  const float* iF   = (const float*)d_in[1];
  const float* w10  = (const float*)d_in[2];
  const float* b10  = (const float*)d_in[3];
  const float* w20  = (const float*)d_in[4];
  const float* b20  = (const float*)d_in[5];
  const float* w11  = (const float*)d_in[6];
  const float* b11  = (const float*)d_in[7];
  const float* w21  = (const float*)d_in[8];
  const float* b21  = (const float*)d_in[9];
  const float* w12  = (const float*)d_in[10];
  const float* b12  = (const float*)d_in[11];
  const float* w22  = (const float*)d_in[12];
  const float* b22  = (const float*)d_in[13];
  const float* wa   = (const float*)d_in[14];
  const float* ba   = (const float*)d_in[15];
  const float* wb   = (const float*)d_in[16];
  const float* bb   = (const float*)d_in[17];
  const float* wo   = (const float*)d_in[18];

  float* outs = (float*)d_out;
  float* alph = outs + (size_t)NB*TB*DOUT;

  lmsc_kernel<<<NB/SPB, 512, 0, stream>>>(x, iF,
      w10, b10, w20, b20, w11, b11, w21, b21, w12, b12, w22, b22,
      wa, ba, wb, bb, wo, outs, alph);
}